// Round 21
// baseline (103.107 us; speedup 1.0000x reference)
//
#include <hip/hip_runtime.h>
#include <hip/hip_bf16.h>
#include <math.h>

#define ALPHA  0.2f
#define BSH    6          // log2(nodes per bucket)
#define BNODES 64         // nodes per bucket
#define NBMAX  1600       // max bucket count (1563 actual)
#define K_CH   4096       // edges per sort-fill block
#define CAPB   2048       // fixed ebuf capacity per bucket (mean 1024, +32 sigma; pow2!)
#define SCH    7          // scan entries per thread (256*7 >= NBMAX)

typedef __attribute__((ext_vector_type(8))) short bf16x8;   // 8 bf16 = 4 VGPRs
typedef __attribute__((ext_vector_type(4))) float f32x4;

static __device__ __forceinline__ unsigned short f2bf(float x) {
    __hip_bfloat16 b = __float2bfloat16(x);
    return *reinterpret_cast<unsigned short*>(&b);
}

// ============ fused prep: blocks [0,gFill) = edge sort; rest = MFMA GEMM ====
// GEMM on matrix cores: 64x64x64 per block, bf16 inputs, f32 accum.
// LDS tiles swizzled byte^=((row&7)<<4) on BOTH write and read (involution;
// row stride 128B would otherwise be a 32-way bank conflict on ds_read_b128).
// Lessons pinned: direct scatter=+19MB writes (R14); fp32 h=+97MB fetch (R18).
__global__ __launch_bounds__(256) void k_prep(
    const float* __restrict__ X, const float* __restrict__ W,
    const float* __restrict__ a, unsigned short* __restrict__ hb,
    float* __restrict__ s_src, float* __restrict__ s_tgt,
    const int* __restrict__ src, const int* __restrict__ tgt,
    int* __restrict__ cur, int* __restrict__ ebuf,
    int N, int E, int nb, int gFill)
{
    __shared__ __align__(16) char smem[37632];
    const int tid = threadIdx.x;

    if (blockIdx.x >= gFill) {
        // ---- part A: h = X @ W via MFMA (bf16 in, f32 acc); 64 rows/block --
        // LDS: Xb bf16[64][64] swizzled @0 (8KB); WbT bf16[64][64] swizzled
        // @8192 (8KB: WbT[n][k] so B-frag k-run is contiguous).
        const int row0 = (blockIdx.x - gFill) * 64;

        // stage X (f32 -> bf16, swizzled 8B stores)
        for (int q = tid; q < 1024; q += 256) {
            int r  = q >> 4;
            int c4 = (q & 15) * 4;
            int row = row0 + r;
            float4 v = make_float4(0.f, 0.f, 0.f, 0.f);
            if (row < N) v = *(const float4*)&X[(size_t)row * 64 + c4];
            ushort4 bv;
            bv.x = f2bf(v.x); bv.y = f2bf(v.y); bv.z = f2bf(v.z); bv.w = f2bf(v.w);
            unsigned byte = (unsigned)r * 128 + (unsigned)c4 * 2;
            byte ^= (unsigned)(r & 7) << 4;          // keeps 8B alignment
            *(ushort4*)(smem + byte) = bv;
        }
        // stage W transposed (W[k][n] f32 -> WbT[n][k] bf16, swizzled)
        for (int q = tid; q < 1024; q += 256) {
            int k  = q >> 4;
            int n0 = (q & 15) * 4;
            float4 v = *(const float4*)&W[k * 64 + n0];
            float vv[4] = {v.x, v.y, v.z, v.w};
#pragma unroll
            for (int i = 0; i < 4; ++i) {
                int n = n0 + i;
                unsigned byte = 8192u + (unsigned)n * 128 + (unsigned)k * 2;
                byte ^= (unsigned)(n & 7) << 4;      // keeps 2B alignment
                *(unsigned short*)(smem + byte) = f2bf(vv[i]);
            }
        }
        __syncthreads();

        const int wv   = tid >> 6;       // wave 0..3: rows [wv*16, wv*16+16)
        const int l    = tid & 63;
        const int lrow = l & 15;         // A row / B col within tile
        const int lk   = (l >> 4) * 8;   // k base within 32-wide half

        // swizzled b128 fragment read (16B granule; xor bits 4-6 preserve align)
        auto frag = [&](unsigned base, int row, int k) -> bf16x8 {
            unsigned byte = base + (unsigned)row * 128 + (unsigned)k * 2;
            byte ^= (unsigned)(row & 7) << 4;
            return *(const bf16x8*)(smem + byte);
        };

        bf16x8 a0 = frag(0u, wv * 16 + lrow, lk);        // A: k in [0,32)
        bf16x8 a1 = frag(0u, wv * 16 + lrow, 32 + lk);   // A: k in [32,64)

        f32x4 acc[4];
#pragma unroll
        for (int t = 0; t < 4; ++t) acc[t] = (f32x4){0.f, 0.f, 0.f, 0.f};

#pragma unroll
        for (int t = 0; t < 4; ++t) {
            bf16x8 b0 = frag(8192u, t * 16 + lrow, lk);
            bf16x8 b1 = frag(8192u, t * 16 + lrow, 32 + lk);
            acc[t] = __builtin_amdgcn_mfma_f32_16x16x32_bf16(a0, b0, acc[t], 0, 0, 0);
            acc[t] = __builtin_amdgcn_mfma_f32_16x16x32_bf16(a1, b1, acc[t], 0, 0, 0);
        }

        // scores from acc: D[row][col], col = t*16 + (l&15),
        // row = wv*16 + (l>>4)*4 + r  (C/D layout, m89-verified)
        float s1p[4] = {0.f, 0.f, 0.f, 0.f};
        float s2p[4] = {0.f, 0.f, 0.f, 0.f};
#pragma unroll
        for (int t = 0; t < 4; ++t) {
            float a1c = a[t * 16 + lrow];
            float a2c = a[64 + t * 16 + lrow];
#pragma unroll
            for (int r = 0; r < 4; ++r) {
                s1p[r] += acc[t][r] * a1c;
                s2p[r] += acc[t][r] * a2c;
            }
        }
#pragma unroll
        for (int r = 0; r < 4; ++r) {
            s1p[r] += __shfl_xor(s1p[r], 1); s2p[r] += __shfl_xor(s2p[r], 1);
            s1p[r] += __shfl_xor(s1p[r], 2); s2p[r] += __shfl_xor(s2p[r], 2);
            s1p[r] += __shfl_xor(s1p[r], 4); s2p[r] += __shfl_xor(s2p[r], 4);
            s1p[r] += __shfl_xor(s1p[r], 8); s2p[r] += __shfl_xor(s2p[r], 8);
        }
        if (lrow == 0) {
#pragma unroll
            for (int r = 0; r < 4; ++r) {
                int row = row0 + wv * 16 + (l >> 4) * 4 + r;
                if (row < N) { s_src[row] = s1p[r]; s_tgt[row] = s2p[r]; }
            }
        }

        // restage D as bf16 in smem[0..8192) linear [64][64], then coalesced out
        __syncthreads();   // all fragment reads done; Xb region reusable
#pragma unroll
        for (int t = 0; t < 4; ++t)
#pragma unroll
            for (int r = 0; r < 4; ++r) {
                int row = wv * 16 + (l >> 4) * 4 + r;
                int col = t * 16 + lrow;
                *(unsigned short*)(smem + (unsigned)row * 128 + (unsigned)col * 2)
                    = f2bf(acc[t][r]);
            }
        __syncthreads();
        for (int q = tid; q < 512; q += 256) {        // 512 uint4 = 8KB
            int row = q >> 3;
            int gr  = row0 + row;
            if (gr < N)
                ((uint4*)&hb[(size_t)gr * 64])[q & 7] = ((const uint4*)smem)[q];
        }
    } else {
        // ---- part D: counting-sort + staged coalesced copy-out (R20) -------
        int* pk    = (int*)smem;              // 16384 B
        int* hist  = (int*)(smem + 16384);    // 6400 B (counts, then cursors)
        int* off_s = (int*)(smem + 22784);    // 6400 B (run starts)
        int* gbase = (int*)(smem + 29184);    // 6400 B (global base per run)
        int* part  = (int*)(smem + 35584);    // 1024 B (scan partials)

        const int blk = blockIdx.x;
        const int e0  = blk * K_CH;
        const int e1  = min(e0 + K_CH, E);
        const int cnt = e1 - e0;

        for (int i = tid; i < nb; i += 256) hist[i] = 0;
        __syncthreads();

        // pass 1: histogram, int4-vectorized (e0 % 4 == 0 by K_CH)
        {
            const int4* t4 = (const int4*)tgt;
            const int v0 = e0 >> 2, v1e = e1 >> 2;
            for (int i = v0 + tid; i < v1e; i += 256) {
                int4 v = t4[i];
                atomicAdd(&hist[v.x >> BSH], 1);
                atomicAdd(&hist[v.y >> BSH], 1);
                atomicAdd(&hist[v.z >> BSH], 1);
                atomicAdd(&hist[v.w >> BSH], 1);
            }
            for (int i = (e1 & ~3) + tid; i < e1; i += 256)   // scalar tail
                atomicAdd(&hist[tgt[i] >> BSH], 1);
        }
        __syncthreads();

        // 3-phase parallel exclusive scan of hist[nb] -> off_s[nb]
        int pref[SCH];
        {
            int s = 0;
            const int i0 = tid * SCH;
#pragma unroll
            for (int j = 0; j < SCH; ++j) {
                int idx = i0 + j;
                int v = (idx < nb) ? hist[idx] : 0;
                pref[j] = s;
                s += v;
            }
            part[tid] = s;
        }
        __syncthreads();
#pragma unroll
        for (int o = 1; o < 256; o <<= 1) {
            int t2 = (tid >= o) ? part[tid - o] : 0;
            __syncthreads();
            part[tid] += t2;
            __syncthreads();
        }
        {
            const int base0 = (tid > 0) ? part[tid - 1] : 0;   // exclusive
            const int i0 = tid * SCH;
#pragma unroll
            for (int j = 0; j < SCH; ++j) {
                int idx = i0 + j;
                if (idx < nb) off_s[idx] = base0 + pref[j];
            }
        }
        __syncthreads();

        // reserve fixed-capacity bucket space; reset cursors to run starts
        for (int i = tid; i < nb; i += 256) {
            int c = hist[i];
            if (c) {
                int within = atomicAdd(&cur[i], c);
                gbase[i] = i * CAPB + within;
            }
            hist[i] = off_s[i];
        }
        __syncthreads();

        // pass 2: scatter into LDS sorted by bucket, int4-vectorized reads
        {
            const int4* t4 = (const int4*)tgt;
            const int4* s4 = (const int4*)src;
            const int v0 = e0 >> 2, v1e = e1 >> 2;
            for (int i = v0 + tid; i < v1e; i += 256) {
                int4 tv = t4[i];
                int4 sv = s4[i];
                int b0 = tv.x >> BSH, p0 = atomicAdd(&hist[b0], 1);
                pk[p0] = sv.x | ((tv.x & (BNODES - 1)) << 17);
                int b1 = tv.y >> BSH, p1 = atomicAdd(&hist[b1], 1);
                pk[p1] = sv.y | ((tv.y & (BNODES - 1)) << 17);
                int b2 = tv.z >> BSH, p2 = atomicAdd(&hist[b2], 1);
                pk[p2] = sv.z | ((tv.z & (BNODES - 1)) << 17);
                int b3 = tv.w >> BSH, p3 = atomicAdd(&hist[b3], 1);
                pk[p3] = sv.w | ((tv.w & (BNODES - 1)) << 17);
            }
            for (int i = (e1 & ~3) + tid; i < e1; i += 256) {  // scalar tail
                int t = tgt[i];
                int b = t >> BSH;
                int p = atomicAdd(&hist[b], 1);
                pk[p] = src[i] | ((t & (BNODES - 1)) << 17);
            }
        }
        __syncthreads();

        // slot-parallel coalesced copy-out (overflow guard via pow2 CAPB)
        for (int i = tid; i < cnt; i += 256) {
            int lo = 0, hi = nb;
            while (hi - lo > 1) {
                int mid = (lo + hi) >> 1;
                if (off_s[mid] <= i) lo = mid; else hi = mid;
            }
            int rel = i - off_s[lo];
            int gb  = gbase[lo];
            if ((gb & (CAPB - 1)) + rel < CAPB) ebuf[gb + rel] = pk[i];
        }
    }
}

// ============ gather: fine sort + edge-parallel exp + 8-edge-in-flight ======
// EXACT R19/R20 structure (proven 57.2us; four inner-loop variants all ~57).
__global__ __launch_bounds__(256) void k_bgather(
    const int* __restrict__ cur, const int* __restrict__ ebuf,
    const float* __restrict__ s_src, const float* __restrict__ s_tgt,
    const uint2* __restrict__ hb2,   // bf16 h rows as 16 uint2
    float* __restrict__ out, int N)
{
    __shared__ uint2 spe[CAPB];      // interleaved {(src<<4), exp-bits}
    __shared__ int   hist[BNODES];
    __shared__ int   off_s[BNODES + 1];
    __shared__ int   cur_s[BNODES];
    __shared__ float sT[BNODES];

    const int tid  = threadIdx.x;
    const int b    = blockIdx.x;
    const int base = b << BSH;
    const int nn   = min(BNODES, N - base);
    const int beg  = b * CAPB;
    const int cnt  = min(cur[b], CAPB);

    if (tid < BNODES) {
        hist[tid] = 0;
        sT[tid] = (base + tid < N) ? s_tgt[base + tid] : 0.f;
    }
    __syncthreads();

    // pass 1: per-node histogram; cache ebuf words in registers (cnt <= 8*256)
    int pkr[8];
#pragma unroll
    for (int j = 0; j < 8; ++j) {
        int i = tid + j * 256;
        pkr[j] = (i < cnt) ? ebuf[beg + i] : -1;
        if (pkr[j] >= 0) atomicAdd(&hist[(pkr[j] >> 17) & (BNODES - 1)], 1);
    }
    __syncthreads();

    if (tid < 64) {                        // single-chunk wave-0 scan
        int v = hist[tid];
        int incl = v;
#pragma unroll
        for (int o = 1; o < 64; o <<= 1) {
            int t2 = __shfl_up(incl, o);
            if (tid >= o) incl += t2;
        }
        off_s[tid + 1] = incl;
        cur_s[tid]     = incl - v;
        if (tid == 0) off_s[0] = 0;
    }
    __syncthreads();

    // pass 2: scatter sorted (from registers) + edge-parallel leaky-relu + exp
#pragma unroll
    for (int j = 0; j < 8; ++j) {
        int pkv = pkr[j];
        if (pkv >= 0) {
            int toff = (pkv >> 17) & (BNODES - 1);
            int sv   = pkv & 0x1FFFF;
            int pos  = atomicAdd(&cur_s[toff], 1);
            float sc = s_src[sv] + sT[toff];
            sc = (sc >= 0.f) ? sc : ALPHA * sc;
            spe[pos] = make_uint2((unsigned)sv << 4,   // 16-slot row base
                                  __float_as_uint(__expf(sc)));
        }
    }
    __syncthreads();

    const int w     = tid >> 6;   // wave 0..3
    const int lane  = tid & 63;
    const int g     = lane >> 4;  // edge group 0..3
    const int fidx2 = lane & 15;  // uint2 (4-feature) slot within row

    for (int tl = w; tl < nn; tl += 4) {
        const int t    = base + tl;
        const int beg2 = off_s[tl];
        const int c    = off_s[tl + 1] - beg2;
        const unsigned ocol = (unsigned)t * 64 + fidx2 * 4;

        if (c == 0) {
            if (g == 0) *(float4*)&out[ocol] = make_float4(0.f, 0.f, 0.f, 0.f);
            continue;
        }

        float ax = 0.f, ay = 0.f, az = 0.f, aw = 0.f, den = 0.f;
        for (int k = 0; k < c; k += 8) {
            int idx0 = k + g;
            int idx1 = k + 4 + g;
            int cl0  = beg2 + min(idx0, c - 1);
            int cl1  = beg2 + min(idx1, c - 1);
            uint2 m0 = spe[cl0];
            uint2 m1 = spe[cl1];
            uint2 u0 = hb2[m0.x + fidx2];
            uint2 u1 = hb2[m1.x + fidx2];
            float p0 = (idx0 < c) ? __uint_as_float(m0.y) : 0.f;
            float p1 = (idx1 < c) ? __uint_as_float(m1.y) : 0.f;
            den += p0;
            ax += p0 * __uint_as_float(u0.x << 16);
            ay += p0 * __uint_as_float(u0.x & 0xFFFF0000u);
            az += p0 * __uint_as_float(u0.y << 16);
            aw += p0 * __uint_as_float(u0.y & 0xFFFF0000u);
            den += p1;
            ax += p1 * __uint_as_float(u1.x << 16);
            ay += p1 * __uint_as_float(u1.x & 0xFFFF0000u);
            az += p1 * __uint_as_float(u1.y << 16);
            aw += p1 * __uint_as_float(u1.y & 0xFFFF0000u);
        }
        // reduce across the 4 groups (lanes differing in bits 4,5)
        ax += __shfl_xor(ax, 16); ay += __shfl_xor(ay, 16);
        az += __shfl_xor(az, 16); aw += __shfl_xor(aw, 16);
        den += __shfl_xor(den, 16);
        ax += __shfl_xor(ax, 32); ay += __shfl_xor(ay, 32);
        az += __shfl_xor(az, 32); aw += __shfl_xor(aw, 32);
        den += __shfl_xor(den, 32);

        if (g == 0) {
            float rd = 1.f / den;
            float r0 = ax * rd, r1 = ay * rd, r2 = az * rd, r3 = aw * rd;
            r0 = (r0 > 0.f) ? r0 : expm1f(r0);
            r1 = (r1 > 0.f) ? r1 : expm1f(r1);
            r2 = (r2 > 0.f) ? r2 : expm1f(r2);
            r3 = (r3 > 0.f) ? r3 : expm1f(r3);
            *(float4*)&out[ocol] = make_float4(r0, r1, r2, r3);
        }
    }
}

extern "C" void kernel_launch(void* const* d_in, const int* in_sizes, int n_in,
                              void* d_out, int out_size, void* d_ws, size_t ws_size,
                              hipStream_t stream)
{
    const float* X  = (const float*)d_in[0];
    const int*   ei = (const int*)d_in[1];
    const float* W  = (const float*)d_in[2];
    const float* a  = (const float*)d_in[3];

    const int N = in_sizes[0] / 64;
    const int E = in_sizes[1] / 2;
    const int* src = ei;
    const int* tgt = ei + E;

    float* out = (float*)d_out;

    const int nb    = (N + BNODES - 1) >> BSH;   // 1563
    const int nbA   = (N + 63) / 64;             // 1563 GEMM blocks
    const int gFill = (E + K_CH - 1) / K_CH;     // 391 sort blocks

    char* ws = (char*)d_ws;
    unsigned short* hb = (unsigned short*)ws; ws += (size_t)N * 64 * sizeof(unsigned short);
    float* s_src  = (float*)ws; ws += (size_t)N * sizeof(float);
    float* s_tgt  = (float*)ws; ws += (size_t)N * sizeof(float);
    int*   cur    = (int*)ws;   ws += (size_t)nb * sizeof(int);
    int*   ebuf   = (int*)ws;   ws += (size_t)nb * CAPB * sizeof(int);

    hipMemsetAsync(cur, 0, (size_t)nb * sizeof(int), stream);

    k_prep    <<<gFill + nbA, 256, 0, stream>>>(X, W, a, hb, s_src, s_tgt,
                                                src, tgt, cur, ebuf, N, E, nb, gFill);
    k_bgather <<<nb, 256, 0, stream>>>(cur, ebuf, s_src, s_tgt,
                                       (const uint2*)hb, out, N);
}

// Round 22
// 100.258 us; speedup vs baseline: 1.0284x; 1.0284x over previous
//
#include <hip/hip_runtime.h>
#include <hip/hip_bf16.h>
#include <math.h>

#define ALPHA  0.2f
#define BSH    6          // log2(nodes per bucket)
#define BNODES 64         // nodes per bucket
#define NBMAX  1600       // max bucket count (1563 actual)
#define K_CH   4096       // edges per sort-fill block
#define CAPB   2048       // fixed ebuf capacity per bucket (mean 1024, +32 sigma; pow2!)
#define SCH    7          // scan entries per thread (256*7 >= NBMAX)

static __device__ __forceinline__ unsigned short f2bf(float x) {
    __hip_bfloat16 b = __float2bfloat16(x);
    return *reinterpret_cast<unsigned short*>(&b);
}

// ============ fused prep: blocks [0,gFill) = edge sort; rest = GEMM =========
// R20-proven (best: 100.6us total). GEMM: 2x8 register tile, 4 LDS inst/k.
// Sort: staged pk[] + slot-parallel binary-search coalesced copy-out.
// Lessons pinned: direct scatter = +19MB writes (R14); XsT staging = +13us
// (R15); fp32 h = +97MB fetch (R18); MFMA GEMM = +2.5us staging tax (R21).
__global__ __launch_bounds__(256) void k_prep(
    const float* __restrict__ X, const float* __restrict__ W,
    const float* __restrict__ a, unsigned short* __restrict__ hb,
    float* __restrict__ s_src, float* __restrict__ s_tgt,
    const int* __restrict__ src, const int* __restrict__ tgt,
    int* __restrict__ cur, int* __restrict__ ebuf,
    int N, int E, int nb, int gFill)
{
    __shared__ __align__(16) char smem[37632];
    const int tid = threadIdx.x;

    if (blockIdx.x >= gFill) {
        // ---- part A: h = X @ W (bf16), node scores; 64 rows/block ----------
        float (*Xs)[65] = (float(*)[65])smem;            // 16640 B
        float (*Ws)[64] = (float(*)[64])(smem + 16640);  // 16384 B
        const int row0 = (blockIdx.x - gFill) * 64;

        {
            const float4* W4 = (const float4*)W;
            float4* Wd = (float4*)&Ws[0][0];
            for (int q = tid; q < 1024; q += 256) Wd[q] = W4[q];
        }
        for (int q = tid; q < 1024; q += 256) {
            int r  = q >> 4;
            int c4 = (q & 15) * 4;
            int row = row0 + r;
            float4 v = make_float4(0.f, 0.f, 0.f, 0.f);
            if (row < N) v = *(const float4*)&X[(size_t)row * 64 + c4];
            Xs[r][c4 + 0] = v.x; Xs[r][c4 + 1] = v.y;
            Xs[r][c4 + 2] = v.z; Xs[r][c4 + 3] = v.w;
        }
        __syncthreads();

        const int cg = (tid & 7) * 8;    // 8 output cols
        const int rg = (tid >> 3) * 2;   // 2 rows (32 groups x 2 = 64)

        float acc[2][8];
#pragma unroll
        for (int r = 0; r < 2; ++r)
#pragma unroll
            for (int c = 0; c < 8; ++c) acc[r][c] = 0.f;

#pragma unroll 8
        for (int k = 0; k < 64; ++k) {
            float4 wv0 = *(const float4*)&Ws[k][cg];
            float4 wv1 = *(const float4*)&Ws[k][cg + 4];
            float x0 = Xs[rg + 0][k];
            float x1 = Xs[rg + 1][k];
            acc[0][0] += x0 * wv0.x; acc[0][1] += x0 * wv0.y;
            acc[0][2] += x0 * wv0.z; acc[0][3] += x0 * wv0.w;
            acc[0][4] += x0 * wv1.x; acc[0][5] += x0 * wv1.y;
            acc[0][6] += x0 * wv1.z; acc[0][7] += x0 * wv1.w;
            acc[1][0] += x1 * wv0.x; acc[1][1] += x1 * wv0.y;
            acc[1][2] += x1 * wv0.z; acc[1][3] += x1 * wv0.w;
            acc[1][4] += x1 * wv1.x; acc[1][5] += x1 * wv1.y;
            acc[1][6] += x1 * wv1.z; acc[1][7] += x1 * wv1.w;
        }

        float a1v[8], a2v[8];
#pragma unroll
        for (int c = 0; c < 8; ++c) { a1v[c] = a[cg + c]; a2v[c] = a[64 + cg + c]; }

#pragma unroll
        for (int r = 0; r < 2; ++r) {
            int row = row0 + rg + r;
            if (row < N) {
                uint4 hv;
                hv.x = (unsigned)f2bf(acc[r][0]) | ((unsigned)f2bf(acc[r][1]) << 16);
                hv.y = (unsigned)f2bf(acc[r][2]) | ((unsigned)f2bf(acc[r][3]) << 16);
                hv.z = (unsigned)f2bf(acc[r][4]) | ((unsigned)f2bf(acc[r][5]) << 16);
                hv.w = (unsigned)f2bf(acc[r][6]) | ((unsigned)f2bf(acc[r][7]) << 16);
                *(uint4*)&hb[(size_t)row * 64 + cg] = hv;   // 16B aligned (cg%8==0)
            }
            float v1 = 0.f, v2 = 0.f;
#pragma unroll
            for (int c = 0; c < 8; ++c) {
                v1 += acc[r][c] * a1v[c];
                v2 += acc[r][c] * a2v[c];
            }
            v1 += __shfl_xor(v1, 1); v2 += __shfl_xor(v2, 1);
            v1 += __shfl_xor(v1, 2); v2 += __shfl_xor(v2, 2);
            v1 += __shfl_xor(v1, 4); v2 += __shfl_xor(v2, 4);
            if ((tid & 7) == 0 && row < N) { s_src[row] = v1; s_tgt[row] = v2; }
        }
    } else {
        // ---- part D: counting-sort + staged coalesced copy-out -------------
        int* pk    = (int*)smem;              // 16384 B
        int* hist  = (int*)(smem + 16384);    // 6400 B (counts, then cursors)
        int* off_s = (int*)(smem + 22784);    // 6400 B (run starts)
        int* gbase = (int*)(smem + 29184);    // 6400 B (global base per run)
        int* part  = (int*)(smem + 35584);    // 1024 B (scan partials)

        const int blk = blockIdx.x;
        const int e0  = blk * K_CH;
        const int e1  = min(e0 + K_CH, E);
        const int cnt = e1 - e0;

        for (int i = tid; i < nb; i += 256) hist[i] = 0;
        __syncthreads();

        // pass 1: histogram, int4-vectorized (e0 % 4 == 0 by K_CH)
        {
            const int4* t4 = (const int4*)tgt;
            const int v0 = e0 >> 2, v1e = e1 >> 2;
            for (int i = v0 + tid; i < v1e; i += 256) {
                int4 v = t4[i];
                atomicAdd(&hist[v.x >> BSH], 1);
                atomicAdd(&hist[v.y >> BSH], 1);
                atomicAdd(&hist[v.z >> BSH], 1);
                atomicAdd(&hist[v.w >> BSH], 1);
            }
            for (int i = (e1 & ~3) + tid; i < e1; i += 256)   // scalar tail
                atomicAdd(&hist[tgt[i] >> BSH], 1);
        }
        __syncthreads();

        // 3-phase parallel exclusive scan of hist[nb] -> off_s[nb]
        int pref[SCH];
        {
            int s = 0;
            const int i0 = tid * SCH;
#pragma unroll
            for (int j = 0; j < SCH; ++j) {
                int idx = i0 + j;
                int v = (idx < nb) ? hist[idx] : 0;
                pref[j] = s;
                s += v;
            }
            part[tid] = s;
        }
        __syncthreads();
#pragma unroll
        for (int o = 1; o < 256; o <<= 1) {
            int t2 = (tid >= o) ? part[tid - o] : 0;
            __syncthreads();
            part[tid] += t2;
            __syncthreads();
        }
        {
            const int base0 = (tid > 0) ? part[tid - 1] : 0;   // exclusive
            const int i0 = tid * SCH;
#pragma unroll
            for (int j = 0; j < SCH; ++j) {
                int idx = i0 + j;
                if (idx < nb) off_s[idx] = base0 + pref[j];
            }
        }
        __syncthreads();

        // reserve fixed-capacity bucket space; reset cursors to run starts
        for (int i = tid; i < nb; i += 256) {
            int c = hist[i];
            if (c) {
                int within = atomicAdd(&cur[i], c);
                gbase[i] = i * CAPB + within;
            }
            hist[i] = off_s[i];
        }
        __syncthreads();

        // pass 2: scatter into LDS sorted by bucket, int4-vectorized reads
        {
            const int4* t4 = (const int4*)tgt;
            const int4* s4 = (const int4*)src;
            const int v0 = e0 >> 2, v1e = e1 >> 2;
            for (int i = v0 + tid; i < v1e; i += 256) {
                int4 tv = t4[i];
                int4 sv = s4[i];
                int b0 = tv.x >> BSH, p0 = atomicAdd(&hist[b0], 1);
                pk[p0] = sv.x | ((tv.x & (BNODES - 1)) << 17);
                int b1 = tv.y >> BSH, p1 = atomicAdd(&hist[b1], 1);
                pk[p1] = sv.y | ((tv.y & (BNODES - 1)) << 17);
                int b2 = tv.z >> BSH, p2 = atomicAdd(&hist[b2], 1);
                pk[p2] = sv.z | ((tv.z & (BNODES - 1)) << 17);
                int b3 = tv.w >> BSH, p3 = atomicAdd(&hist[b3], 1);
                pk[p3] = sv.w | ((tv.w & (BNODES - 1)) << 17);
            }
            for (int i = (e1 & ~3) + tid; i < e1; i += 256) {  // scalar tail
                int t = tgt[i];
                int b = t >> BSH;
                int p = atomicAdd(&hist[b], 1);
                pk[p] = src[i] | ((t & (BNODES - 1)) << 17);
            }
        }
        __syncthreads();

        // slot-parallel coalesced copy-out (overflow guard via pow2 CAPB)
        for (int i = tid; i < cnt; i += 256) {
            int lo = 0, hi = nb;
            while (hi - lo > 1) {
                int mid = (lo + hi) >> 1;
                if (off_s[mid] <= i) lo = mid; else hi = mid;
            }
            int rel = i - off_s[lo];
            int gb  = gbase[lo];
            if ((gb & (CAPB - 1)) + rel < CAPB) ebuf[gb + rel] = pk[i];
        }
    }
}

// ============ gather: fine sort + edge-parallel exp + 8-edge-in-flight ======
// EXACT R19/R20 structure (57.2us; four inner-loop variants all ~57 -> floor).
__global__ __launch_bounds__(256) void k_bgather(
    const int* __restrict__ cur, const int* __restrict__ ebuf,
    const float* __restrict__ s_src, const float* __restrict__ s_tgt,
    const uint2* __restrict__ hb2,   // bf16 h rows as 16 uint2
    float* __restrict__ out, int N)
{
    __shared__ uint2 spe[CAPB];      // interleaved {(src<<4), exp-bits}
    __shared__ int   hist[BNODES];
    __shared__ int   off_s[BNODES + 1];
    __shared__ int   cur_s[BNODES];
    __shared__ float sT[BNODES];

    const int tid  = threadIdx.x;
    const int b    = blockIdx.x;
    const int base = b << BSH;
    const int nn   = min(BNODES, N - base);
    const int beg  = b * CAPB;
    const int cnt  = min(cur[b], CAPB);

    if (tid < BNODES) {
        hist[tid] = 0;
        sT[tid] = (base + tid < N) ? s_tgt[base + tid] : 0.f;
    }
    __syncthreads();

    // pass 1: per-node histogram; cache ebuf words in registers (cnt <= 8*256)
    int pkr[8];
#pragma unroll
    for (int j = 0; j < 8; ++j) {
        int i = tid + j * 256;
        pkr[j] = (i < cnt) ? ebuf[beg + i] : -1;
        if (pkr[j] >= 0) atomicAdd(&hist[(pkr[j] >> 17) & (BNODES - 1)], 1);
    }
    __syncthreads();

    if (tid < 64) {                        // single-chunk wave-0 scan
        int v = hist[tid];
        int incl = v;
#pragma unroll
        for (int o = 1; o < 64; o <<= 1) {
            int t2 = __shfl_up(incl, o);
            if (tid >= o) incl += t2;
        }
        off_s[tid + 1] = incl;
        cur_s[tid]     = incl - v;
        if (tid == 0) off_s[0] = 0;
    }
    __syncthreads();

    // pass 2: scatter sorted (from registers) + edge-parallel leaky-relu + exp
#pragma unroll
    for (int j = 0; j < 8; ++j) {
        int pkv = pkr[j];
        if (pkv >= 0) {
            int toff = (pkv >> 17) & (BNODES - 1);
            int sv   = pkv & 0x1FFFF;
            int pos  = atomicAdd(&cur_s[toff], 1);
            float sc = s_src[sv] + sT[toff];
            sc = (sc >= 0.f) ? sc : ALPHA * sc;
            spe[pos] = make_uint2((unsigned)sv << 4,   // 16-slot row base
                                  __float_as_uint(__expf(sc)));
        }
    }
    __syncthreads();

    const int w     = tid >> 6;   // wave 0..3
    const int lane  = tid & 63;
    const int g     = lane >> 4;  // edge group 0..3
    const int fidx2 = lane & 15;  // uint2 (4-feature) slot within row

    for (int tl = w; tl < nn; tl += 4) {
        const int t    = base + tl;
        const int beg2 = off_s[tl];
        const int c    = off_s[tl + 1] - beg2;
        const unsigned ocol = (unsigned)t * 64 + fidx2 * 4;

        if (c == 0) {
            if (g == 0) *(float4*)&out[ocol] = make_float4(0.f, 0.f, 0.f, 0.f);
            continue;
        }

        float ax = 0.f, ay = 0.f, az = 0.f, aw = 0.f, den = 0.f;
        for (int k = 0; k < c; k += 8) {
            int idx0 = k + g;
            int idx1 = k + 4 + g;
            int cl0  = beg2 + min(idx0, c - 1);
            int cl1  = beg2 + min(idx1, c - 1);
            uint2 m0 = spe[cl0];
            uint2 m1 = spe[cl1];
            uint2 u0 = hb2[m0.x + fidx2];
            uint2 u1 = hb2[m1.x + fidx2];
            float p0 = (idx0 < c) ? __uint_as_float(m0.y) : 0.f;
            float p1 = (idx1 < c) ? __uint_as_float(m1.y) : 0.f;
            den += p0;
            ax += p0 * __uint_as_float(u0.x << 16);
            ay += p0 * __uint_as_float(u0.x & 0xFFFF0000u);
            az += p0 * __uint_as_float(u0.y << 16);
            aw += p0 * __uint_as_float(u0.y & 0xFFFF0000u);
            den += p1;
            ax += p1 * __uint_as_float(u1.x << 16);
            ay += p1 * __uint_as_float(u1.x & 0xFFFF0000u);
            az += p1 * __uint_as_float(u1.y << 16);
            aw += p1 * __uint_as_float(u1.y & 0xFFFF0000u);
        }
        // reduce across the 4 groups (lanes differing in bits 4,5)
        ax += __shfl_xor(ax, 16); ay += __shfl_xor(ay, 16);
        az += __shfl_xor(az, 16); aw += __shfl_xor(aw, 16);
        den += __shfl_xor(den, 16);
        ax += __shfl_xor(ax, 32); ay += __shfl_xor(ay, 32);
        az += __shfl_xor(az, 32); aw += __shfl_xor(aw, 32);
        den += __shfl_xor(den, 32);

        if (g == 0) {
            float rd = 1.f / den;
            float r0 = ax * rd, r1 = ay * rd, r2 = az * rd, r3 = aw * rd;
            r0 = (r0 > 0.f) ? r0 : expm1f(r0);
            r1 = (r1 > 0.f) ? r1 : expm1f(r1);
            r2 = (r2 > 0.f) ? r2 : expm1f(r2);
            r3 = (r3 > 0.f) ? r3 : expm1f(r3);
            *(float4*)&out[ocol] = make_float4(r0, r1, r2, r3);
        }
    }
}

extern "C" void kernel_launch(void* const* d_in, const int* in_sizes, int n_in,
                              void* d_out, int out_size, void* d_ws, size_t ws_size,
                              hipStream_t stream)
{
    const float* X  = (const float*)d_in[0];
    const int*   ei = (const int*)d_in[1];
    const float* W  = (const float*)d_in[2];
    const float* a  = (const float*)d_in[3];

    const int N = in_sizes[0] / 64;
    const int E = in_sizes[1] / 2;
    const int* src = ei;
    const int* tgt = ei + E;

    float* out = (float*)d_out;

    const int nb    = (N + BNODES - 1) >> BSH;   // 1563
    const int nbA   = (N + 63) / 64;             // 1563 GEMM blocks
    const int gFill = (E + K_CH - 1) / K_CH;     // 391 sort blocks

    char* ws = (char*)d_ws;
    unsigned short* hb = (unsigned short*)ws; ws += (size_t)N * 64 * sizeof(unsigned short);
    float* s_src  = (float*)ws; ws += (size_t)N * sizeof(float);
    float* s_tgt  = (float*)ws; ws += (size_t)N * sizeof(float);
    int*   cur    = (int*)ws;   ws += (size_t)nb * sizeof(int);
    int*   ebuf   = (int*)ws;   ws += (size_t)nb * CAPB * sizeof(int);

    hipMemsetAsync(cur, 0, (size_t)nb * sizeof(int), stream);

    k_prep    <<<gFill + nbA, 256, 0, stream>>>(X, W, a, hb, s_src, s_tgt,
                                                src, tgt, cur, ebuf, N, E, nb, gFill);
    k_bgather <<<nb, 256, 0, stream>>>(cur, ebuf, s_src, s_tgt,
                                       (const uint2*)hb, out, N);
}